// Round 4
// baseline (326.693 us; speedup 1.0000x reference)
//
#include <hip/hip_runtime.h>

// ---------------------------------------------------------------------------
// Order-preserving f32 <-> u32 key mapping.
// key(f) is monotonically increasing with f; key==0 corresponds to bit pattern
// 0xFFFFFFFF (a NaN), which no real input produces -> 0 is the atomicMax
// identity AND the "empty segment" sentinel.
// ---------------------------------------------------------------------------
__device__ __forceinline__ unsigned int f32_key(float f) {
    unsigned int b = __float_as_uint(f);
    return (b & 0x80000000u) ? ~b : (b | 0x80000000u);
}
__device__ __forceinline__ float key_f32(unsigned int k) {
    unsigned int b = (k & 0x80000000u) ? (k ^ 0x80000000u) : ~k;
    return __uint_as_float(b);
}

// ---------------------------------------------------------------------------
// Kernel 1: per-block min of phi -> blockmin[blockIdx]
// ---------------------------------------------------------------------------
__global__ __launch_bounds__(256) void phimin_kernel(
    const float* __restrict__ phi, int n, float* __restrict__ blockmin)
{
    int tid    = blockIdx.x * blockDim.x + threadIdx.x;
    int stride = gridDim.x * blockDim.x;

    float m = 3.4028235e38f;
    int n4 = n >> 2;
    const float4* p4 = (const float4*)phi;
    for (int i = tid; i < n4; i += stride) {
        float4 v = p4[i];
        m = fminf(m, fminf(fminf(v.x, v.y), fminf(v.z, v.w)));
    }
    // scalar tail (none for 4M, but stay generic)
    for (int i = (n4 << 2) + tid; i < n; i += stride)
        m = fminf(m, phi[i]);

    #pragma unroll
    for (int off = 32; off >= 1; off >>= 1)
        m = fminf(m, __shfl_down(m, off, 64));

    __shared__ float lds[4];
    int lane = threadIdx.x & 63, wid = threadIdx.x >> 6;
    if (lane == 0) lds[wid] = m;
    __syncthreads();
    if (threadIdx.x == 0)
        blockmin[blockIdx.x] = fminf(fminf(lds[0], lds[1]), fminf(lds[2], lds[3]));
}

// ---------------------------------------------------------------------------
// Kernel 2: segmented max. Each thread owns V=32 contiguous elements.
// segment_ids are sorted -> per-thread run-length max, one atomicMax per
// segment boundary encountered (~2 per thread on average).
// ---------------------------------------------------------------------------
__global__ __launch_bounds__(256) void segmax_kernel(
    const float* __restrict__ phi,
    const int*   __restrict__ indices,
    const int*   __restrict__ segids,
    unsigned int* out,            // keys, pre-zeroed
    int total)
{
    const int V = 32;
    long base = (long)(blockIdx.x * blockDim.x + threadIdx.x) * V;
    if (base >= total) return;

    int cur = -1;
    float m = 0.0f;

    if (base + V <= (long)total) {
        const int4* idx4 = (const int4*)(indices + base);
        const int4* seg4 = (const int4*)(segids  + base);
        #pragma unroll
        for (int c = 0; c < V / 8; ++c) {
            int4 i0 = idx4[c * 2 + 0];
            int4 i1 = idx4[c * 2 + 1];
            int4 s0 = seg4[c * 2 + 0];
            int4 s1 = seg4[c * 2 + 1];
            // 8 independent gathers -> good MLP; phi table is L2/L3 resident
            float v[8];
            v[0] = phi[i0.x]; v[1] = phi[i0.y]; v[2] = phi[i0.z]; v[3] = phi[i0.w];
            v[4] = phi[i1.x]; v[5] = phi[i1.y]; v[6] = phi[i1.z]; v[7] = phi[i1.w];
            int s[8] = { s0.x, s0.y, s0.z, s0.w, s1.x, s1.y, s1.z, s1.w };
            #pragma unroll
            for (int e = 0; e < 8; ++e) {
                if (s[e] != cur) {
                    if (cur >= 0) atomicMax(&out[cur], f32_key(m));
                    cur = s[e];
                    m   = v[e];
                } else {
                    m = fmaxf(m, v[e]);
                }
            }
        }
    } else {
        // generic tail (unused at the bench sizes, kept for safety)
        for (long i = base; i < (long)total; ++i) {
            int s   = segids[i];
            float v = phi[indices[i]];
            if (s != cur) {
                if (cur >= 0) atomicMax(&out[cur], f32_key(m));
                cur = s;
                m   = v;
            } else {
                m = fmaxf(m, v);
            }
        }
    }
    if (cur >= 0) atomicMax(&out[cur], f32_key(m));
}

// ---------------------------------------------------------------------------
// Kernel 3: reduce block mins -> phi_min; decode keys in place, fill empties.
// ---------------------------------------------------------------------------
__global__ __launch_bounds__(256) void finalize_kernel(
    const float* __restrict__ blockmin, int nbm,
    unsigned int* out_u, float* out_f, int nseg)
{
    float m = 3.4028235e38f;
    for (int i = threadIdx.x; i < nbm; i += blockDim.x)
        m = fminf(m, blockmin[i]);
    #pragma unroll
    for (int off = 32; off >= 1; off >>= 1)
        m = fminf(m, __shfl_down(m, off, 64));

    __shared__ float lds[4];
    __shared__ float s_phimin;
    int lane = threadIdx.x & 63, wid = threadIdx.x >> 6;
    if (lane == 0) lds[wid] = m;
    __syncthreads();
    if (threadIdx.x == 0)
        s_phimin = fminf(fminf(lds[0], lds[1]), fminf(lds[2], lds[3]));
    __syncthreads();
    float phimin = s_phimin;

    int tid    = blockIdx.x * blockDim.x + threadIdx.x;
    int stride = gridDim.x * blockDim.x;
    for (int i = tid; i < nseg; i += stride) {
        unsigned int k = out_u[i];
        out_f[i] = (k == 0u) ? phimin : key_f32(k);
    }
}

// ---------------------------------------------------------------------------
// Launcher
// ---------------------------------------------------------------------------
extern "C" void kernel_launch(void* const* d_in, const int* in_sizes, int n_in,
                              void* d_out, int out_size, void* d_ws, size_t ws_size,
                              hipStream_t stream)
{
    const float* phi     = (const float*)d_in[0];
    const int*   indices = (const int*)d_in[1];
    const int*   segids  = (const int*)d_in[2];

    int num_atoms = in_sizes[0];
    int total     = in_sizes[1];
    int nseg      = out_size;

    unsigned int* out_u    = (unsigned int*)d_out;
    float*        out_f    = (float*)d_out;
    float*        blockmin = (float*)d_ws;

    const int PMIN_BLOCKS = 1024;

    // identity/empty sentinel: key 0
    hipMemsetAsync(d_out, 0, (size_t)nseg * sizeof(float), stream);

    phimin_kernel<<<PMIN_BLOCKS, 256, 0, stream>>>(phi, num_atoms, blockmin);

    int threads = (total + 31) / 32;
    int blocks  = (threads + 255) / 256;
    segmax_kernel<<<blocks, 256, 0, stream>>>(phi, indices, segids, out_u, total);

    finalize_kernel<<<512, 256, 0, stream>>>(blockmin, PMIN_BLOCKS, out_u, out_f, nseg);
}